// Round 11
// baseline (104923.535 us; speedup 1.0000x reference)
//
#include <hip/hip_runtime.h>
#include <cstdint>
#include <cstddef>

typedef unsigned long long u64;

// ---------------- problem constants ----------------
#define TSTEPS 2000
#define NB     256      // batch
#define CIN    14

// ---------------- workspace layout (bytes) ----------------
// S2c/S2s (reordered layer-2 weights) OVERLAY the BN-partials region,
// which is dead after k1b.
#define OFF_FEAT 0ull                       // [256][128] f32 = 131072
#define OFF_AB   131072ull                  // a[64], b[64] = 512
#define OFF_PART 131584ull                  // f32 [2304][64][2] = 1179648
#define OFF_S2C  131584ull                  // 131072 B  (alias PART)
#define OFF_S2S  (OFF_S2C + 131072ull)      // 393216 B  (alias PART)
#define OFF_MASK (OFF_PART + 1179648ull)    // u64 [2000][256] = 4096000

// ============================================================
// K1: conv1d -> per-(b,tile) partial sum/sumsq for BN
// ============================================================
__global__ __launch_bounds__(256) void k1_stats(const float* __restrict__ x,
                                                const float* __restrict__ cw,
                                                float* __restrict__ part) {
  __shared__ float xLds[244 * CIN];
  __shared__ float cwLds[64 * 70];
  __shared__ float red[2][4][64];
  const int b = blockIdx.x, tile = blockIdx.y;
  const int base = tile * 240;
  for (int f = threadIdx.x; f < 244 * CIN; f += 256) {
    int u = f / CIN, ci = f - u * CIN;
    int tp = base + u - 2;
    xLds[f] = (tp >= 0 && tp < TSTEPS) ? x[((size_t)tp * NB + b) * CIN + ci] : 0.0f;
  }
  for (int f = threadIdx.x; f < 64 * 70; f += 256) cwLds[f] = cw[f];
  __syncthreads();

  const int co = threadIdx.x & 63, tq = threadIdx.x >> 6;
  float cwr[70];
#pragma unroll
  for (int s = 0; s < 70; ++s) cwr[s] = cwLds[co * 70 + s];
  float xw[5][CIN];
  const int u0 = tq * 60;
#pragma unroll
  for (int r = 0; r < 4; ++r)
#pragma unroll
    for (int ci = 0; ci < CIN; ++ci) xw[r][ci] = xLds[(u0 + r) * CIN + ci];

  float s1 = 0.0f, s2 = 0.0f;
  const int tbase = base + tq * 60;
  for (int i5 = 0; i5 < 60; i5 += 5) {
#pragma unroll
    for (int s = 0; s < 5; ++s) {
#pragma unroll
      for (int ci = 0; ci < CIN; ++ci)
        xw[(s + 4) % 5][ci] = xLds[(u0 + i5 + s + 4) * CIN + ci];
      float y = 0.0f;
#pragma unroll
      for (int kk = 0; kk < 5; ++kk)
#pragma unroll
        for (int ci = 0; ci < CIN; ++ci)
          y += xw[(s + kk) % 5][ci] * cwr[ci * 5 + kk];
      if (tbase + i5 + s < TSTEPS) { s1 += y; s2 += y * y; }
    }
  }
  red[0][tq][co] = s1; red[1][tq][co] = s2;
  __syncthreads();
  if (threadIdx.x < 64) {
    float a1 = red[0][0][co] + red[0][1][co] + red[0][2][co] + red[0][3][co];
    float a2 = red[1][0][co] + red[1][1][co] + red[1][2][co] + red[1][3][co];
    int blk = tile * NB + b;
    part[blk * 128 + co * 2 + 0] = a1;
    part[blk * 128 + co * 2 + 1] = a2;
  }
}

// K1b: deterministic fixed-order reduction of partials -> a[co], b[co]
__global__ __launch_bounds__(256) void k1b_reduce(const float* __restrict__ gamma,
                           const float* __restrict__ beta,
                           const float* __restrict__ part, float* __restrict__ ab) {
  __shared__ float red[2][4][64];
  const int co = threadIdx.x & 63, pt = threadIdx.x >> 6;
  float s1 = 0.0f, s2 = 0.0f;
  for (int blk = pt * 576; blk < pt * 576 + 576; ++blk) {
    s1 += part[blk * 128 + co * 2 + 0];
    s2 += part[blk * 128 + co * 2 + 1];
  }
  red[0][pt][co] = s1; red[1][pt][co] = s2;
  __syncthreads();
  if (threadIdx.x < 64) {
    float a1 = red[0][0][co] + red[0][1][co] + red[0][2][co] + red[0][3][co];
    float a2 = red[1][0][co] + red[1][1][co] + red[1][2][co] + red[1][3][co];
    const float N = (float)TSTEPS * (float)NB;
    float mu = a1 / N;
    float var = a2 / N - mu * mu;
    float rstd = 1.0f / sqrtf(var + 1e-5f);
    float a = gamma[co] * rstd;
    ab[co] = a;
    ab[64 + co] = beta[co] - mu * a;
  }
}

// ============================================================
// K2: conv1d -> BN -> spike -> pack 64 channel bits into u64 per (t,b)
// ============================================================
__global__ __launch_bounds__(256) void k2_spike(const float* __restrict__ x,
                                                const float* __restrict__ cw,
                                                const float* __restrict__ thrp,
                                                const float* __restrict__ ab,
                                                u64* __restrict__ masks) {
  __shared__ float xLds[244 * CIN];
  __shared__ float cwLds[64 * 70];
  const int b = blockIdx.x, tile = blockIdx.y;
  const int base = tile * 240;
  for (int f = threadIdx.x; f < 244 * CIN; f += 256) {
    int u = f / CIN, ci = f - u * CIN;
    int tp = base + u - 2;
    xLds[f] = (tp >= 0 && tp < TSTEPS) ? x[((size_t)tp * NB + b) * CIN + ci] : 0.0f;
  }
  for (int f = threadIdx.x; f < 64 * 70; f += 256) cwLds[f] = cw[f];
  __syncthreads();

  const int co = threadIdx.x & 63, tq = threadIdx.x >> 6;
  const float thr = thrp[0];
  const float aC = ab[co], bC = ab[64 + co];
  float cwr[70];
#pragma unroll
  for (int s = 0; s < 70; ++s) cwr[s] = cwLds[co * 70 + s];
  float xw[5][CIN];
  const int u0 = tq * 60;
#pragma unroll
  for (int r = 0; r < 4; ++r)
#pragma unroll
    for (int ci = 0; ci < CIN; ++ci) xw[r][ci] = xLds[(u0 + r) * CIN + ci];

  const int tbase = base + tq * 60;
  for (int i5 = 0; i5 < 60; i5 += 5) {
#pragma unroll
    for (int s = 0; s < 5; ++s) {
#pragma unroll
      for (int ci = 0; ci < CIN; ++ci)
        xw[(s + 4) % 5][ci] = xLds[(u0 + i5 + s + 4) * CIN + ci];
      float y = 0.0f;
#pragma unroll
      for (int kk = 0; kk < 5; ++kk)
#pragma unroll
        for (int ci = 0; ci < CIN; ++ci)
          y += xw[(s + kk) % 5][ci] * cwr[ci * 5 + kk];
      int t = tbase + i5 + s;
      if (t < TSTEPS) {
        float bn = y * aC + bC;
        u64 m = __ballot(bn - thr > 0.0f);  // lane i = channel i
        if (co == 0) masks[(size_t)t * NB + b] = m;
      }
    }
  }
}

// ============================================================
// KWP: reorder layer-2 weights for conflict-free streaming.
// S2c: [mc 0..8)[slot 0..64)[kq 0..8)[jj 0..8)  (k<64 of w_ih2, LDS-cached)
// S2s: [ms 0..24)[slot][kq][jj]                 (m=ms+8: rest of w_ih2 + w_hh2)
// GEMM2 k for m: m<16 -> k=m*8+kq (spk region); else k=128+(m-16)*8+kq (mem2).
// ============================================================
__global__ __launch_bounds__(256) void k_wprep(const float* __restrict__ w_ih2,
                                               const float* __restrict__ w_hh2,
                                               float* __restrict__ S2c,
                                               float* __restrict__ S2s) {
  int f = blockIdx.x * 256 + threadIdx.x;
  if (f < 32768) {
    int jj = f & 7, kq = (f >> 3) & 7, slot = (f >> 6) & 63, mc = f >> 12;
    S2c[f] = w_ih2[(slot * 8 + jj) * 128 + mc * 8 + kq];
  } else if (f < 131072) {
    int fs = f - 32768;
    int jj = fs & 7, kq = (fs >> 3) & 7, slot = (fs >> 6) & 63, ms = fs >> 12;
    int m = ms + 8, j = slot * 8 + jj;
    S2s[fs] = (m < 16) ? w_ih2[j * 128 + m * 8 + kq]
                       : w_hh2[j * 128 + (m - 16) * 8 + kq];
  }
}

// ============================================================
// KP_LOCAL: block-local two-layer SLSTM. 128 blocks x 512 threads;
// block b owns batch rows {2b, 2b+1} and ALL h for both layers.
// ZERO inter-block communication: recurrent state in LDS/registers;
// L1 weights in 192 VGPRs/thread; L2 weights streamed from (XCD-L2-
// resident) global each step, 128KB of them cached in LDS.
// 3 __syncthreads per step; no atomics, no spins, no flags.
// Thread map: kq = tid&7 (8-way k-split), slot = tid>>3; each thread
// computes 8 gate rows j = slot*8+jj for 2 rows; shfl_xor 1/2/4 reduce.
// ============================================================
__device__ __forceinline__ float sigm(float v) { return 1.0f / (1.0f + expf(-v)); }

__global__ __launch_bounds__(512, 2) void kp_local(char* ws,
    const float* __restrict__ w_ih1, const float* __restrict__ w_hh1,
    const float* __restrict__ b_ih1, const float* __restrict__ b_hh1,
    const float* __restrict__ thr1p,
    const float* __restrict__ b_ih2, const float* __restrict__ b_hh2,
    const float* __restrict__ thr2p) {
  extern __shared__ float wc[];              // 32768 floats = 128 KB w2 cache
  __shared__ float x1buf[192 * 2];           // [k][r]: k<64 conv spk, k>=64 mem1
  __shared__ float x2buf[256 * 2];           // [k][r]: k<128 spk1, k>=128 mem2
  __shared__ float g1[512 * 2], g2[512 * 2]; // gates [j][r]
  __shared__ float bias1L[512], bias2L[512];

  const int tid = threadIdx.x;
  const int bid = blockIdx.x;                // rows 2*bid, 2*bid+1
  const int kq = tid & 7, slot = tid >> 3;
  const int j0 = slot * 8;

  const float* S2c = (const float*)(ws + OFF_S2C);
  const float* S2s = (const float*)(ws + OFF_S2S);
  float* feat = (float*)(ws + OFF_FEAT);
  const u64* masks = (const u64*)(ws + OFF_MASK);

  // ---- one-time: L1 weights -> 192 registers (k = m*8+kq interleave) ----
  float w1r[24][8];
#pragma unroll
  for (int m = 0; m < 24; ++m) {
    const int k = m * 8 + kq;
#pragma unroll
    for (int jj = 0; jj < 8; ++jj)
      w1r[m][jj] = (k < 64) ? w_ih1[(j0 + jj) * 64 + k]
                            : w_hh1[(j0 + jj) * 128 + (k - 64)];
  }
  bias1L[tid] = b_ih1[tid] + b_hh1[tid];
  bias2L[tid] = b_ih2[tid] + b_hh2[tid];
  for (int f = tid; f < 32768; f += 512) wc[f] = S2c[f];
  x2buf[tid] = 0.0f;                         // spk1(0-) / mem2(-1) = 0
  if (tid >= 128 && tid < 384) x1buf[tid] = 0.0f;   // mem1(-1) = 0
  if (tid >= 384) {                          // conv spikes for step 0
    int idx = tid - 384;                     // k = idx>>1, r = idx&1
    u64 m0 = masks[(size_t)0 * NB + 2 * bid + (idx & 1)];
    x1buf[(idx >> 1) * 2 + (idx & 1)] = (float)((m0 >> (idx >> 1)) & 1ull);
  }
  const float thr1 = thr1p[0], thr2 = thr2p[0];
  const int hC = tid & 127, rC = (tid >> 7) & 1;    // cell map (tid<256)
  float syn1 = 0.0f, mem1 = 0.0f, syn2 = 0.0f, mem2 = 0.0f, facc = 0.0f;
  __syncthreads();

  for (int p = 0; p < TSTEPS; ++p) {
    // prefetch next conv mask (for the conv-writer threads)
    u64 mnext = 0;
    if (tid >= 384 && p + 1 < TSTEPS)
      mnext = masks[(size_t)(p + 1) * NB + 2 * bid + ((tid - 384) & 1)];

    // ---- GEMM1: K=192, all from x1buf (LDS) + register weights ----
    float a0[8], a1[8];
#pragma unroll
    for (int jj = 0; jj < 8; ++jj) { a0[jj] = 0.0f; a1[jj] = 0.0f; }
#pragma unroll
    for (int m = 0; m < 24; ++m) {
      float2 xv = *(const float2*)&x1buf[(m * 8 + kq) * 2];
#pragma unroll
      for (int jj = 0; jj < 8; ++jj) {
        a0[jj] += w1r[m][jj] * xv.x; a1[jj] += w1r[m][jj] * xv.y;
      }
    }
#pragma unroll
    for (int jj = 0; jj < 8; ++jj) {
      a0[jj] += __shfl_xor(a0[jj], 1); a1[jj] += __shfl_xor(a1[jj], 1);
      a0[jj] += __shfl_xor(a0[jj], 2); a1[jj] += __shfl_xor(a1[jj], 2);
      a0[jj] += __shfl_xor(a0[jj], 4); a1[jj] += __shfl_xor(a1[jj], 4);
    }
    if (kq == 0) {
#pragma unroll
      for (int jj = 0; jj < 8; ++jj) {
        g1[(j0 + jj) * 2 + 0] = a0[jj]; g1[(j0 + jj) * 2 + 1] = a1[jj];
      }
    }
    __syncthreads();   // B1: g1 ready; x1buf conv(p) consumed

    // ---- cell1 (tid<256) || conv(p+1) writers (tid>=384) ----
    if (tid < 256) {
      float gi = bias1L[hC]        + g1[(hC) * 2 + rC];
      float gf = bias1L[128 + hC]  + g1[(128 + hC) * 2 + rC];
      float gg = bias1L[256 + hC]  + g1[(256 + hC) * 2 + rC];
      float go = bias1L[384 + hC]  + g1[(384 + hC) * 2 + rC];
      float rst = (mem1 - thr1 > 0.0f) ? thr1 : 0.0f;
      float cn = sigm(gf) * syn1 + sigm(gi) * tanhf(gg);
      float mn = sigm(go) * tanhf(cn) - rst;
      syn1 = cn; mem1 = mn;
      x1buf[(64 + hC) * 2 + rC] = mn;                       // mem1(p)
      x2buf[hC * 2 + rC] = (mn - thr1 > 0.0f) ? 1.0f : 0.0f; // spk1(p)
    } else if (tid >= 384 && p + 1 < TSTEPS) {
      int idx = tid - 384;
      x1buf[(idx >> 1) * 2 + (idx & 1)] =
          (float)((mnext >> (idx >> 1)) & 1ull);            // conv(p+1)
    }
    __syncthreads();   // B2: x2buf spk(p) + x1buf(p+1 inputs) ready

    // ---- GEMM2: K=256; weights from LDS cache (m<8) + L2 stream ----
#pragma unroll
    for (int jj = 0; jj < 8; ++jj) { a0[jj] = 0.0f; a1[jj] = 0.0f; }
#pragma unroll
    for (int mc = 0; mc < 8; ++mc) {
      const float* wv = &wc[((mc * 64 + slot) * 8 + kq) * 8];
      float2 xv = *(const float2*)&x2buf[(mc * 8 + kq) * 2];
#pragma unroll
      for (int jj = 0; jj < 8; ++jj) {
        float w = wv[jj];
        a0[jj] += w * xv.x; a1[jj] += w * xv.y;
      }
    }
#pragma unroll 4
    for (int ms = 0; ms < 24; ++ms) {
      const int m = ms + 8;
      const float* sp = &S2s[(((size_t)ms * 64 + slot) * 8 + kq) * 8];
      float4 wv0 = *(const float4*)sp;
      float4 wv1 = *(const float4*)(sp + 4);
      const int k2 = (m < 16) ? (m * 8 + kq) : (128 + (m - 16) * 8 + kq);
      float2 xv = *(const float2*)&x2buf[k2 * 2];
      a0[0] += wv0.x * xv.x; a1[0] += wv0.x * xv.y;
      a0[1] += wv0.y * xv.x; a1[1] += wv0.y * xv.y;
      a0[2] += wv0.z * xv.x; a1[2] += wv0.z * xv.y;
      a0[3] += wv0.w * xv.x; a1[3] += wv0.w * xv.y;
      a0[4] += wv1.x * xv.x; a1[4] += wv1.x * xv.y;
      a0[5] += wv1.y * xv.x; a1[5] += wv1.y * xv.y;
      a0[6] += wv1.z * xv.x; a1[6] += wv1.z * xv.y;
      a0[7] += wv1.w * xv.x; a1[7] += wv1.w * xv.y;
    }
#pragma unroll
    for (int jj = 0; jj < 8; ++jj) {
      a0[jj] += __shfl_xor(a0[jj], 1); a1[jj] += __shfl_xor(a1[jj], 1);
      a0[jj] += __shfl_xor(a0[jj], 2); a1[jj] += __shfl_xor(a1[jj], 2);
      a0[jj] += __shfl_xor(a0[jj], 4); a1[jj] += __shfl_xor(a1[jj], 4);
    }
    if (kq == 0) {
#pragma unroll
      for (int jj = 0; jj < 8; ++jj) {
        g2[(j0 + jj) * 2 + 0] = a0[jj]; g2[(j0 + jj) * 2 + 1] = a1[jj];
      }
    }
    __syncthreads();   // B3: g2 ready

    // ---- cell2 (tid<256); no trailing barrier needed:
    // next GEMM1 touches only x1buf/g1; x2buf-mem2 consumers (GEMM2(p+1))
    // are separated by B2(p+1), and cell threads pass it only after this.
    if (tid < 256) {
      float gi = bias2L[hC]        + g2[(hC) * 2 + rC];
      float gf = bias2L[128 + hC]  + g2[(128 + hC) * 2 + rC];
      float gg = bias2L[256 + hC]  + g2[(256 + hC) * 2 + rC];
      float go = bias2L[384 + hC]  + g2[(384 + hC) * 2 + rC];
      float rst = (mem2 - thr2 > 0.0f) ? thr2 : 0.0f;
      float cn = sigm(gf) * syn2 + sigm(gi) * tanhf(gg);
      float mn = sigm(go) * tanhf(cn) - rst;
      syn2 = cn; mem2 = mn;
      x2buf[(128 + hC) * 2 + rC] = mn;                      // mem2(p)
      facc += mn;
    }
  }

  if (tid < 256)
    feat[(size_t)(2 * bid + rC) * 128 + hC] = facc * (1.0f / (float)TSTEPS);
}

// ============================================================
// K3: head — gesture + (binary) domain_hidden -> domain
// ============================================================
__global__ __launch_bounds__(128) void k3_head(const float* __restrict__ feat,
    const float* __restrict__ gw, const float* __restrict__ gb,
    const float* __restrict__ d1w, const float* __restrict__ d1b,
    const float* __restrict__ thrdp,
    const float* __restrict__ d2w, const float* __restrict__ d2b,
    float* __restrict__ out) {
  __shared__ float fL[128];
  __shared__ float dh[64];
  const int b = blockIdx.x, t = threadIdx.x;
  fL[t] = feat[b * 128 + t];
  __syncthreads();
  if (t < 64) {
    float s = d1b[t];
    for (int k = 0; k < 128; ++k) s += d1w[t * 128 + k] * fL[k];
    dh[t] = (s - thrdp[0] > 0.0f) ? 1.0f : 0.0f;
  }
  __syncthreads();
  if (t < 8) {
    float s = gb[t];
    for (int k = 0; k < 128; ++k) s += gw[t * 128 + k] * fL[k];
    out[b * 8 + t] = s;
  }
  if (t >= 64 && t < 74) {
    const int o = t - 64;
    float s = d2b[o];
    for (int k = 0; k < 64; ++k) s += d2w[o * 64 + k] * dh[k];
    out[2048 + b * 10 + o] = s;
  }
}

// ============================================================
extern "C" void kernel_launch(void* const* d_in, const int* in_sizes, int n_in,
                              void* d_out, int out_size, void* d_ws, size_t ws_size,
                              hipStream_t stream) {
  const float* x      = (const float*)d_in[0];
  const float* conv_w = (const float*)d_in[1];
  const float* bn_g   = (const float*)d_in[2];
  const float* bn_b   = (const float*)d_in[3];
  const float* thrl1  = (const float*)d_in[4];
  const float* w_ih1  = (const float*)d_in[5];
  const float* w_hh1  = (const float*)d_in[6];
  const float* b_ih1  = (const float*)d_in[7];
  const float* b_hh1  = (const float*)d_in[8];
  const float* thr1   = (const float*)d_in[9];
  const float* w_ih2  = (const float*)d_in[10];
  const float* w_hh2  = (const float*)d_in[11];
  const float* b_ih2  = (const float*)d_in[12];
  const float* b_hh2  = (const float*)d_in[13];
  const float* thr2   = (const float*)d_in[14];
  const float* fc_g_w = (const float*)d_in[15];
  const float* fc_g_b = (const float*)d_in[16];
  const float* fc_d1w = (const float*)d_in[17];
  const float* fc_d1b = (const float*)d_in[18];
  const float* thrdom = (const float*)d_in[19];
  const float* fc_d2w = (const float*)d_in[20];
  const float* fc_d2b = (const float*)d_in[21];
  float* out = (float*)d_out;
  char* ws = (char*)d_ws;

  k1_stats<<<dim3(NB, 9), 256, 0, stream>>>(x, conv_w, (float*)(ws + OFF_PART));
  k1b_reduce<<<1, 256, 0, stream>>>(bn_g, bn_b, (const float*)(ws + OFF_PART),
                                    (float*)(ws + OFF_AB));
  k2_spike<<<dim3(NB, 9), 256, 0, stream>>>(x, conv_w, thrl1,
                                            (const float*)(ws + OFF_AB),
                                            (u64*)(ws + OFF_MASK));
  // reorder L2 weights into stream layout (overlays dead PART region)
  k_wprep<<<512, 256, 0, stream>>>(w_ih2, w_hh2,
                                   (float*)(ws + OFF_S2C), (float*)(ws + OFF_S2S));
  // 128 KB dynamic LDS (w2 cache) + ~16 KB static; 1 block/CU; no sync
  kp_local<<<128, 512, 131072, stream>>>(ws, w_ih1, w_hh1, b_ih1, b_hh1, thr1,
                                         b_ih2, b_hh2, thr2);
  k3_head<<<NB, 128, 0, stream>>>((const float*)(ws + OFF_FEAT), fc_g_w, fc_g_b,
                                  fc_d1w, fc_d1b, thrdom, fc_d2w, fc_d2b, out);
}

// Round 12
// 20031.039 us; speedup vs baseline: 5.2380x; 5.2380x over previous
//
#include <hip/hip_runtime.h>
#include <cstdint>
#include <cstddef>

typedef unsigned long long u64;

// ---------------- problem constants ----------------
#define TSTEPS 2000
#define NB     256      // batch
#define CIN    14

// ---------------- workspace layout (bytes) ----------------
// WS (reordered weights, 917504 B) OVERLAYS the BN-partials region,
// which is dead after k1b.
#define OFF_FEAT 0ull                       // [256][128] f32 = 131072
#define OFF_AB   131072ull                  // a[64], b[64] = 512
#define OFF_PART 131584ull                  // f32 [2304][64][2] = 1179648
#define OFF_WS   131584ull                  // f32 [56][64][8][8] = 917504 (alias)
#define OFF_MASK (OFF_PART + 1179648ull)    // u64 [2000][256] = 4096000

// ============================================================
// K1: conv1d -> per-(b,tile) partial sum/sumsq for BN
// ============================================================
__global__ __launch_bounds__(256) void k1_stats(const float* __restrict__ x,
                                                const float* __restrict__ cw,
                                                float* __restrict__ part) {
  __shared__ float xLds[244 * CIN];
  __shared__ float cwLds[64 * 70];
  __shared__ float red[2][4][64];
  const int b = blockIdx.x, tile = blockIdx.y;
  const int base = tile * 240;
  for (int f = threadIdx.x; f < 244 * CIN; f += 256) {
    int u = f / CIN, ci = f - u * CIN;
    int tp = base + u - 2;
    xLds[f] = (tp >= 0 && tp < TSTEPS) ? x[((size_t)tp * NB + b) * CIN + ci] : 0.0f;
  }
  for (int f = threadIdx.x; f < 64 * 70; f += 256) cwLds[f] = cw[f];
  __syncthreads();

  const int co = threadIdx.x & 63, tq = threadIdx.x >> 6;
  float cwr[70];
#pragma unroll
  for (int s = 0; s < 70; ++s) cwr[s] = cwLds[co * 70 + s];
  float xw[5][CIN];
  const int u0 = tq * 60;
#pragma unroll
  for (int r = 0; r < 4; ++r)
#pragma unroll
    for (int ci = 0; ci < CIN; ++ci) xw[r][ci] = xLds[(u0 + r) * CIN + ci];

  float s1 = 0.0f, s2 = 0.0f;
  const int tbase = base + tq * 60;
  for (int i5 = 0; i5 < 60; i5 += 5) {
#pragma unroll
    for (int s = 0; s < 5; ++s) {
#pragma unroll
      for (int ci = 0; ci < CIN; ++ci)
        xw[(s + 4) % 5][ci] = xLds[(u0 + i5 + s + 4) * CIN + ci];
      float y = 0.0f;
#pragma unroll
      for (int kk = 0; kk < 5; ++kk)
#pragma unroll
        for (int ci = 0; ci < CIN; ++ci)
          y += xw[(s + kk) % 5][ci] * cwr[ci * 5 + kk];
      if (tbase + i5 + s < TSTEPS) { s1 += y; s2 += y * y; }
    }
  }
  red[0][tq][co] = s1; red[1][tq][co] = s2;
  __syncthreads();
  if (threadIdx.x < 64) {
    float a1 = red[0][0][co] + red[0][1][co] + red[0][2][co] + red[0][3][co];
    float a2 = red[1][0][co] + red[1][1][co] + red[1][2][co] + red[1][3][co];
    int blk = tile * NB + b;
    part[blk * 128 + co * 2 + 0] = a1;
    part[blk * 128 + co * 2 + 1] = a2;
  }
}

// K1b: deterministic fixed-order reduction of partials -> a[co], b[co]
__global__ __launch_bounds__(256) void k1b_reduce(const float* __restrict__ gamma,
                           const float* __restrict__ beta,
                           const float* __restrict__ part, float* __restrict__ ab) {
  __shared__ float red[2][4][64];
  const int co = threadIdx.x & 63, pt = threadIdx.x >> 6;
  float s1 = 0.0f, s2 = 0.0f;
  for (int blk = pt * 576; blk < pt * 576 + 576; ++blk) {
    s1 += part[blk * 128 + co * 2 + 0];
    s2 += part[blk * 128 + co * 2 + 1];
  }
  red[0][pt][co] = s1; red[1][pt][co] = s2;
  __syncthreads();
  if (threadIdx.x < 64) {
    float a1 = red[0][0][co] + red[0][1][co] + red[0][2][co] + red[0][3][co];
    float a2 = red[1][0][co] + red[1][1][co] + red[1][2][co] + red[1][3][co];
    const float N = (float)TSTEPS * (float)NB;
    float mu = a1 / N;
    float var = a2 / N - mu * mu;
    float rstd = 1.0f / sqrtf(var + 1e-5f);
    float a = gamma[co] * rstd;
    ab[co] = a;
    ab[64 + co] = beta[co] - mu * a;
  }
}

// ============================================================
// K2: conv1d -> BN -> spike -> pack 64 channel bits into u64 per (t,b)
// ============================================================
__global__ __launch_bounds__(256) void k2_spike(const float* __restrict__ x,
                                                const float* __restrict__ cw,
                                                const float* __restrict__ thrp,
                                                const float* __restrict__ ab,
                                                u64* __restrict__ masks) {
  __shared__ float xLds[244 * CIN];
  __shared__ float cwLds[64 * 70];
  const int b = blockIdx.x, tile = blockIdx.y;
  const int base = tile * 240;
  for (int f = threadIdx.x; f < 244 * CIN; f += 256) {
    int u = f / CIN, ci = f - u * CIN;
    int tp = base + u - 2;
    xLds[f] = (tp >= 0 && tp < TSTEPS) ? x[((size_t)tp * NB + b) * CIN + ci] : 0.0f;
  }
  for (int f = threadIdx.x; f < 64 * 70; f += 256) cwLds[f] = cw[f];
  __syncthreads();

  const int co = threadIdx.x & 63, tq = threadIdx.x >> 6;
  const float thr = thrp[0];
  const float aC = ab[co], bC = ab[64 + co];
  float cwr[70];
#pragma unroll
  for (int s = 0; s < 70; ++s) cwr[s] = cwLds[co * 70 + s];
  float xw[5][CIN];
  const int u0 = tq * 60;
#pragma unroll
  for (int r = 0; r < 4; ++r)
#pragma unroll
    for (int ci = 0; ci < CIN; ++ci) xw[r][ci] = xLds[(u0 + r) * CIN + ci];

  const int tbase = base + tq * 60;
  for (int i5 = 0; i5 < 60; i5 += 5) {
#pragma unroll
    for (int s = 0; s < 5; ++s) {
#pragma unroll
      for (int ci = 0; ci < CIN; ++ci)
        xw[(s + 4) % 5][ci] = xLds[(u0 + i5 + s + 4) * CIN + ci];
      float y = 0.0f;
#pragma unroll
      for (int kk = 0; kk < 5; ++kk)
#pragma unroll
        for (int ci = 0; ci < CIN; ++ci)
          y += xw[(s + kk) % 5][ci] * cwr[ci * 5 + kk];
      int t = tbase + i5 + s;
      if (t < TSTEPS) {
        float bn = y * aC + bC;
        u64 m = __ballot(bn - thr > 0.0f);  // lane i = channel i
        if (co == 0) masks[(size_t)t * NB + b] = m;
      }
    }
  }
}

// ============================================================
// KWP: reorder ALL recurrent weights into stream layout
// WS[mt 0..56)[slot 0..64)[kq 0..8)[jj 0..8)]:
//   mt<24 : GEMM1, j=slot*8+jj, k=mt*8+kq (k<64 w_ih1, else w_hh1)
//   mt>=24: GEMM2, m=mt-24, k=m*8+kq (k<128 w_ih2, else w_hh2)
// ============================================================
__global__ __launch_bounds__(256) void k_wprep(const float* __restrict__ w_ih1,
                                               const float* __restrict__ w_hh1,
                                               const float* __restrict__ w_ih2,
                                               const float* __restrict__ w_hh2,
                                               float* __restrict__ WS) {
  int f = blockIdx.x * 256 + threadIdx.x;
  if (f >= 229376) return;
  int mt = f >> 12, rem = f & 4095;
  int slot = rem >> 6, kq = (rem >> 3) & 7, jj = rem & 7;
  int j = slot * 8 + jj;
  float w;
  if (mt < 24) {
    int k = mt * 8 + kq;
    w = (k < 64) ? w_ih1[j * 64 + k] : w_hh1[j * 128 + (k - 64)];
  } else {
    int k = (mt - 24) * 8 + kq;
    w = (k < 128) ? w_ih2[j * 128 + k] : w_hh2[j * 128 + (k - 128)];
  }
  WS[f] = w;
}

// ============================================================
// KP_LOCAL: block-local two-layer SLSTM (r11 structure, spill-free).
// 128 blocks x 512 threads; block owns rows {2b,2b+1}, all h, both layers.
// Zero inter-block communication. NO register-resident weights:
//  - 8 m-slices (128KB) cached in LDS, layout [m][jj][slot][kq]
//    -> scalar reads are 2-lanes/bank (free).
//  - remaining 48 slices streamed from XCD-L2 each step as coalesced
//    float4 pairs (weights L2-resident: 917KB/XCD).
// 3 __syncthreads/step. Arithmetic order identical to r11 (absmax 0.0).
// ============================================================
__device__ __forceinline__ float sigm(float v) { return 1.0f / (1.0f + expf(-v)); }

__global__ __launch_bounds__(512) void kp_local(char* ws,
    const float* __restrict__ b_ih1, const float* __restrict__ b_hh1,
    const float* __restrict__ thr1p,
    const float* __restrict__ b_ih2, const float* __restrict__ b_hh2,
    const float* __restrict__ thr2p) {
  extern __shared__ float wc[];              // 32768 floats = 128 KB
  __shared__ float x1buf[192 * 2];           // [k][r]: k<64 conv, k>=64 mem1
  __shared__ float x2buf[256 * 2];           // [k][r]: k<128 spk1, k>=128 mem2
  __shared__ float g1[512 * 2], g2[512 * 2]; // gates [j][r]
  __shared__ float bias1L[512], bias2L[512];

  const int tid = threadIdx.x;
  const int bid = blockIdx.x;                // rows 2*bid, 2*bid+1
  const int kq = tid & 7, slot = tid >> 3;
  const int j0 = slot * 8;

  const float* WS = (const float*)(ws + OFF_WS);
  float* feat = (float*)(ws + OFF_FEAT);
  const u64* masks = (const u64*)(ws + OFF_MASK);

  // ---- one-time: fill LDS weight cache (slices 0..7, transposed) ----
  for (int f = tid; f < 32768; f += 512) {
    int m = f >> 12, jj = (f >> 9) & 7, sl = (f >> 3) & 63, kk = f & 7;
    wc[f] = WS[m * 4096 + sl * 64 + kk * 8 + jj];
  }
  bias1L[tid] = b_ih1[tid] + b_hh1[tid];
  bias2L[tid] = b_ih2[tid] + b_hh2[tid];
  x2buf[tid] = 0.0f;                         // spk1 / mem2 init 0
  if (tid >= 128 && tid < 384) x1buf[tid] = 0.0f;   // mem1(-1) = 0
  if (tid >= 384) {                          // conv spikes for step 0
    int idx = tid - 384;                     // k = idx>>1, r = idx&1
    u64 m0 = masks[(size_t)0 * NB + 2 * bid + (idx & 1)];
    x1buf[(idx >> 1) * 2 + (idx & 1)] = (float)((m0 >> (idx >> 1)) & 1ull);
  }
  const float thr1 = thr1p[0], thr2 = thr2p[0];
  const int hC = tid & 127, rC = (tid >> 7) & 1;    // cell map (tid<256)
  float syn1 = 0.0f, mem1 = 0.0f, syn2 = 0.0f, mem2 = 0.0f, facc = 0.0f;
  __syncthreads();

#define FMA8V(w0_, w1_, xv_)                                                   \
  a0[0] += w0_.x * xv_.x; a1[0] += w0_.x * xv_.y;                              \
  a0[1] += w0_.y * xv_.x; a1[1] += w0_.y * xv_.y;                              \
  a0[2] += w0_.z * xv_.x; a1[2] += w0_.z * xv_.y;                              \
  a0[3] += w0_.w * xv_.x; a1[3] += w0_.w * xv_.y;                              \
  a0[4] += w1_.x * xv_.x; a1[4] += w1_.x * xv_.y;                              \
  a0[5] += w1_.y * xv_.x; a1[5] += w1_.y * xv_.y;                              \
  a0[6] += w1_.z * xv_.x; a1[6] += w1_.z * xv_.y;                              \
  a0[7] += w1_.w * xv_.x; a1[7] += w1_.w * xv_.y;

  for (int p = 0; p < TSTEPS; ++p) {
    // prefetch next conv mask (conv-writer threads)
    u64 mnext = 0;
    if (tid >= 384 && p + 1 < TSTEPS)
      mnext = masks[(size_t)(p + 1) * NB + 2 * bid + ((tid - 384) & 1)];

    // ---- GEMM1: K=192 (m 0..7 LDS-cached, m 8..23 L2-streamed) ----
    float a0[8], a1[8];
#pragma unroll
    for (int jj = 0; jj < 8; ++jj) { a0[jj] = 0.0f; a1[jj] = 0.0f; }
#pragma unroll
    for (int m = 0; m < 8; ++m) {
      float2 xv = *(const float2*)&x1buf[(m * 8 + kq) * 2];
      const float* wp = &wc[m * 4096 + slot * 8 + kq];
#pragma unroll
      for (int jj = 0; jj < 8; ++jj) {
        float w = wp[jj * 512];
        a0[jj] += w * xv.x; a1[jj] += w * xv.y;
      }
    }
#pragma unroll 8
    for (int m = 8; m < 24; ++m) {
      const float* sp = WS + (size_t)m * 4096 + slot * 64 + kq * 8;
      float4 w0 = *(const float4*)sp;
      float4 w1 = *(const float4*)(sp + 4);
      float2 xv = *(const float2*)&x1buf[(m * 8 + kq) * 2];
      FMA8V(w0, w1, xv);
    }
#pragma unroll
    for (int jj = 0; jj < 8; ++jj) {
      a0[jj] += __shfl_xor(a0[jj], 1); a1[jj] += __shfl_xor(a1[jj], 1);
      a0[jj] += __shfl_xor(a0[jj], 2); a1[jj] += __shfl_xor(a1[jj], 2);
      a0[jj] += __shfl_xor(a0[jj], 4); a1[jj] += __shfl_xor(a1[jj], 4);
    }
    if (kq == 0) {
#pragma unroll
      for (int jj = 0; jj < 8; ++jj) {
        g1[(j0 + jj) * 2 + 0] = a0[jj]; g1[(j0 + jj) * 2 + 1] = a1[jj];
      }
    }
    __syncthreads();   // B1: g1 ready; x1buf conv(p) consumed

    // ---- cell1 (tid<256) || conv(p+1) writers (tid>=384) ----
    if (tid < 256) {
      float gi = bias1L[hC]        + g1[(hC) * 2 + rC];
      float gf = bias1L[128 + hC]  + g1[(128 + hC) * 2 + rC];
      float gg = bias1L[256 + hC]  + g1[(256 + hC) * 2 + rC];
      float go = bias1L[384 + hC]  + g1[(384 + hC) * 2 + rC];
      float rst = (mem1 - thr1 > 0.0f) ? thr1 : 0.0f;
      float cn = sigm(gf) * syn1 + sigm(gi) * tanhf(gg);
      float mn = sigm(go) * tanhf(cn) - rst;
      syn1 = cn; mem1 = mn;
      x1buf[(64 + hC) * 2 + rC] = mn;                        // mem1(p)
      x2buf[hC * 2 + rC] = (mn - thr1 > 0.0f) ? 1.0f : 0.0f; // spk1(p)
    } else if (tid >= 384 && p + 1 < TSTEPS) {
      int idx = tid - 384;
      x1buf[(idx >> 1) * 2 + (idx & 1)] =
          (float)((mnext >> (idx >> 1)) & 1ull);             // conv(p+1)
    }
    __syncthreads();   // B2: x2buf spk(p) + x1buf(p+1 inputs) ready

    // ---- GEMM2: K=256, all streamed from L2 (slices 24..55) ----
#pragma unroll
    for (int jj = 0; jj < 8; ++jj) { a0[jj] = 0.0f; a1[jj] = 0.0f; }
#pragma unroll 8
    for (int m = 0; m < 32; ++m) {
      const float* sp = WS + (size_t)(24 + m) * 4096 + slot * 64 + kq * 8;
      float4 w0 = *(const float4*)sp;
      float4 w1 = *(const float4*)(sp + 4);
      float2 xv = *(const float2*)&x2buf[(m * 8 + kq) * 2];
      FMA8V(w0, w1, xv);
    }
#pragma unroll
    for (int jj = 0; jj < 8; ++jj) {
      a0[jj] += __shfl_xor(a0[jj], 1); a1[jj] += __shfl_xor(a1[jj], 1);
      a0[jj] += __shfl_xor(a0[jj], 2); a1[jj] += __shfl_xor(a1[jj], 2);
      a0[jj] += __shfl_xor(a0[jj], 4); a1[jj] += __shfl_xor(a1[jj], 4);
    }
    if (kq == 0) {
#pragma unroll
      for (int jj = 0; jj < 8; ++jj) {
        g2[(j0 + jj) * 2 + 0] = a0[jj]; g2[(j0 + jj) * 2 + 1] = a1[jj];
      }
    }
    __syncthreads();   // B3: g2 ready

    // ---- cell2 (tid<256); no trailing barrier needed (see r11 note) ----
    if (tid < 256) {
      float gi = bias2L[hC]        + g2[(hC) * 2 + rC];
      float gf = bias2L[128 + hC]  + g2[(128 + hC) * 2 + rC];
      float gg = bias2L[256 + hC]  + g2[(256 + hC) * 2 + rC];
      float go = bias2L[384 + hC]  + g2[(384 + hC) * 2 + rC];
      float rst = (mem2 - thr2 > 0.0f) ? thr2 : 0.0f;
      float cn = sigm(gf) * syn2 + sigm(gi) * tanhf(gg);
      float mn = sigm(go) * tanhf(cn) - rst;
      syn2 = cn; mem2 = mn;
      x2buf[(128 + hC) * 2 + rC] = mn;                       // mem2(p)
      facc += mn;
    }
  }

  if (tid < 256)
    feat[(size_t)(2 * bid + rC) * 128 + hC] = facc * (1.0f / (float)TSTEPS);
#undef FMA8V
}

// ============================================================
// K3: head — gesture + (binary) domain_hidden -> domain
// ============================================================
__global__ __launch_bounds__(128) void k3_head(const float* __restrict__ feat,
    const float* __restrict__ gw, const float* __restrict__ gb,
    const float* __restrict__ d1w, const float* __restrict__ d1b,
    const float* __restrict__ thrdp,
    const float* __restrict__ d2w, const float* __restrict__ d2b,
    float* __restrict__ out) {
  __shared__ float fL[128];
  __shared__ float dh[64];
  const int b = blockIdx.x, t = threadIdx.x;
  fL[t] = feat[b * 128 + t];
  __syncthreads();
  if (t < 64) {
    float s = d1b[t];
    for (int k = 0; k < 128; ++k) s += d1w[t * 128 + k] * fL[k];
    dh[t] = (s - thrdp[0] > 0.0f) ? 1.0f : 0.0f;
  }
  __syncthreads();
  if (t < 8) {
    float s = gb[t];
    for (int k = 0; k < 128; ++k) s += gw[t * 128 + k] * fL[k];
    out[b * 8 + t] = s;
  }
  if (t >= 64 && t < 74) {
    const int o = t - 64;
    float s = d2b[o];
    for (int k = 0; k < 64; ++k) s += d2w[o * 64 + k] * dh[k];
    out[2048 + b * 10 + o] = s;
  }
}

// ============================================================
extern "C" void kernel_launch(void* const* d_in, const int* in_sizes, int n_in,
                              void* d_out, int out_size, void* d_ws, size_t ws_size,
                              hipStream_t stream) {
  const float* x      = (const float*)d_in[0];
  const float* conv_w = (const float*)d_in[1];
  const float* bn_g   = (const float*)d_in[2];
  const float* bn_b   = (const float*)d_in[3];
  const float* thrl1  = (const float*)d_in[4];
  const float* w_ih1  = (const float*)d_in[5];
  const float* w_hh1  = (const float*)d_in[6];
  const float* b_ih1  = (const float*)d_in[7];
  const float* b_hh1  = (const float*)d_in[8];
  const float* thr1   = (const float*)d_in[9];
  const float* w_ih2  = (const float*)d_in[10];
  const float* w_hh2  = (const float*)d_in[11];
  const float* b_ih2  = (const float*)d_in[12];
  const float* b_hh2  = (const float*)d_in[13];
  const float* thr2   = (const float*)d_in[14];
  const float* fc_g_w = (const float*)d_in[15];
  const float* fc_g_b = (const float*)d_in[16];
  const float* fc_d1w = (const float*)d_in[17];
  const float* fc_d1b = (const float*)d_in[18];
  const float* thrdom = (const float*)d_in[19];
  const float* fc_d2w = (const float*)d_in[20];
  const float* fc_d2b = (const float*)d_in[21];
  float* out = (float*)d_out;
  char* ws = (char*)d_ws;

  k1_stats<<<dim3(NB, 9), 256, 0, stream>>>(x, conv_w, (float*)(ws + OFF_PART));
  k1b_reduce<<<1, 256, 0, stream>>>(bn_g, bn_b, (const float*)(ws + OFF_PART),
                                    (float*)(ws + OFF_AB));
  k2_spike<<<dim3(NB, 9), 256, 0, stream>>>(x, conv_w, thrl1,
                                            (const float*)(ws + OFF_AB),
                                            (u64*)(ws + OFF_MASK));
  // reorder all recurrent weights into stream layout (overlays dead PART)
  k_wprep<<<896, 256, 0, stream>>>(w_ih1, w_hh1, w_ih2, w_hh2,
                                   (float*)(ws + OFF_WS));
  // 128 KB dynamic LDS (weight cache); 1 block/CU; zero inter-block sync
  kp_local<<<128, 512, 131072, stream>>>(ws, b_ih1, b_hh1, thr1,
                                         b_ih2, b_hh2, thr2);
  k3_head<<<NB, 128, 0, stream>>>((const float*)(ws + OFF_FEAT), fc_g_w, fc_g_b,
                                  fc_d1w, fc_d1b, thrdom, fc_d2w, fc_d2b, out);
}